// Round 24
// baseline (129.522 us; speedup 1.0000x reference)
//
#include <hip/hip_runtime.h>

#define HID 32
#define SH 9                 // bucket covers 512 nodes
#define BNODES 512
#define NBMAX 320            // >= ceil(150000/512)=293
#define TILE 8192            // edges per bucketize block
#define CAP 16384            // fixed ebuf capacity per bucket (2x mean load)
#define STAGECAP 12288       // LDS edge staging in k_sortb (48 KB)

typedef unsigned int uint;

__device__ __forceinline__ uint f2bf(float v) {   // RNE f32 -> bf16 bits
    uint b = __float_as_uint(v);
    return (b + 0x7fffu + ((b >> 16) & 1u)) >> 16;
}

// ---- zero bcur ----
__global__ void k_zero(int* __restrict__ p, int n) {
    int i = blockIdx.x * 256 + threadIdx.x;
    if (i < n) p[i] = 0;
}

// ---- bucketize: int4 loads -> LDS counting sort by bucket -> bump-allocated chunk append ----
// ebuf layout: bucket b owns slots [b*CAP, b*CAP + bcur[b]). packed word: src | (dlow<<18)
__global__ void __launch_bounds__(512) k_bucketize(
        const int* __restrict__ src, const int* __restrict__ dst,
        int* __restrict__ bcur, uint* __restrict__ ebuf, int E, int NB) {
    __shared__ uint  ecache[TILE];
    __shared__ unsigned short bcache[TILE];
    __shared__ int cnt[NBMAX];
    __shared__ int loff[NBMAX + 1];
    __shared__ int gbase[NBMAX];
    int tid = threadIdx.x;
    int tbase = blockIdx.x * TILE;
    int tcount = min(E - tbase, TILE);
    int tc4 = tcount >> 2;
    const int4* dst4 = (const int4*)(dst + tbase);
    const int4* src4 = (const int4*)(src + tbase);

    for (int b = tid; b < NBMAX; b += 512) cnt[b] = 0;
    __syncthreads();
    // phase 1: count (vectorized)
#pragma unroll
    for (int k = 0; k < TILE / 4 / 512; ++k) {
        int q = k * 512 + tid;
        if (q < tc4) {
            int4 d = dst4[q];
            atomicAdd(&cnt[d.x >> SH], 1);
            atomicAdd(&cnt[d.y >> SH], 1);
            atomicAdd(&cnt[d.z >> SH], 1);
            atomicAdd(&cnt[d.w >> SH], 1);
        }
    }
    if (tid == 0)
        for (int t = tc4 << 2; t < tcount; ++t) atomicAdd(&cnt[dst[tbase + t] >> SH], 1);
    __syncthreads();
    // phase 2: scan (wave 0), 64 lanes x 5 buckets
    if (tid < 64) {
        int lo = tid * 5;
        int s = 0;
        for (int b = lo; b < lo + 5 && b < NB; ++b) s += cnt[b];
        int v = s;
        for (int off = 1; off < 64; off <<= 1) {
            int u = __shfl_up(v, off, 64);
            if (tid >= off) v += u;
        }
        int excl = v - s;
        for (int b = lo; b < lo + 5 && b < NB; ++b) { loff[b] = excl; excl += cnt[b]; }
        if (tid == 63) loff[NB] = excl;
    }
    __syncthreads();
    for (int b = tid; b < NB; b += 512) cnt[b] = loff[b];
    __syncthreads();
    // phase 3: place into LDS ordered by bucket (vectorized loads)
#pragma unroll
    for (int k = 0; k < TILE / 4 / 512; ++k) {
        int q = k * 512 + tid;
        if (q < tc4) {
            int4 d = dst4[q];
            int4 s = src4[q];
            int b0 = d.x >> SH, p0 = atomicAdd(&cnt[b0], 1);
            ecache[p0] = (uint)s.x | ((uint)(d.x & (BNODES - 1)) << 18); bcache[p0] = (unsigned short)b0;
            int b1 = d.y >> SH, p1_ = atomicAdd(&cnt[b1], 1);
            ecache[p1_] = (uint)s.y | ((uint)(d.y & (BNODES - 1)) << 18); bcache[p1_] = (unsigned short)b1;
            int b2 = d.z >> SH, p2_ = atomicAdd(&cnt[b2], 1);
            ecache[p2_] = (uint)s.z | ((uint)(d.z & (BNODES - 1)) << 18); bcache[p2_] = (unsigned short)b2;
            int b3 = d.w >> SH, p3_ = atomicAdd(&cnt[b3], 1);
            ecache[p3_] = (uint)s.w | ((uint)(d.w & (BNODES - 1)) << 18); bcache[p3_] = (unsigned short)b3;
        }
    }
    if (tid == 0)
        for (int t = tc4 << 2; t < tcount; ++t) {
            int d = dst[tbase + t];
            int b_ = d >> SH;
            int pos = atomicAdd(&cnt[b_], 1);
            ecache[pos] = (uint)src[tbase + t] | ((uint)(d & (BNODES - 1)) << 18);
            bcache[pos] = (unsigned short)b_;
        }
    __syncthreads();
    // phase 4: reserve chunk in fixed-stride bucket region (bump allocator)
    for (int b = tid; b < NB; b += 512) {
        int tc = loff[b + 1] - loff[b];
        if (tc > 0) gbase[b] = b * CAP + atomicAdd(&bcur[b], tc);
    }
    __syncthreads();
    // phase 5: contiguous write-out
    for (int j = tid; j < tcount; j += 512) {
        int b = bcache[j];
        ebuf[gbase[b] + (j - loff[b])] = ecache[j];
    }
}

// ---- exclusive scan of actual bucket counts (bcur) -> CSR bases; rowptr[N] = E ----
__global__ void k_scanb(const int* __restrict__ bcur, int* __restrict__ bbase,
                        int* __restrict__ rowptr, int N, int NB) {
    __shared__ int l[NBMAX + 1];
    int tid = threadIdx.x;
    if (tid < 64) {
        int lo = tid * 5;
        int s = 0;
        for (int b = lo; b < lo + 5 && b < NB; ++b) s += bcur[b];
        int v = s;
        for (int off = 1; off < 64; off <<= 1) {
            int u = __shfl_up(v, off, 64);
            if (tid >= off) v += u;
        }
        int excl = v - s;
        for (int b = lo; b < lo + 5 && b < NB; ++b) { l[b] = excl; excl += bcur[b]; }
        if (tid == 63) l[NB] = excl;
    }
    __syncthreads();
    for (int b = tid; b <= NB; b += blockDim.x) bbase[b] = l[b];
    if (tid == 0) rowptr[N] = l[NB];
}

// ---- per-bucket counting sort by node + degree-sorted node permutation ----
__global__ void __launch_bounds__(512) k_sortb(
        const uint* __restrict__ ebuf, const int* __restrict__ bcur,
        const int* __restrict__ bbase, const float* __restrict__ x,
        int* __restrict__ rowptr, float* __restrict__ dinv,
        float2* __restrict__ p1, int* __restrict__ col,
        int* __restrict__ nodeperm, int N) {
    __shared__ int c[BNODES];
    __shared__ int off[BNODES];
    __shared__ int cur[BNODES];
    __shared__ int dbin[64];
    __shared__ int dcur[64];
    __shared__ uint stage[STAGECAP];   // 48 KB edge staging
    int b = blockIdx.x, tid = threadIdx.x;
    int cnt = bcur[b];
    const uint* eb = ebuf + (long)b * CAP;   // 16B-aligned (CAP % 4 == 0)
    int cbase = bbase[b];
    int nnodes = min(BNODES, N - (b << SH));
    for (int t = tid; t < BNODES; t += 512) c[t] = 0;
    if (tid < 64) dbin[tid] = 0;
    __syncthreads();
    // count pass: uint4 loads, stage into LDS
    int vc = cnt >> 2;
    const uint4* e4 = (const uint4*)eb;
    for (int q = tid; q < vc; q += 512) {
        uint4 e = e4[q];
        atomicAdd(&c[e.x >> 18], 1);
        atomicAdd(&c[e.y >> 18], 1);
        atomicAdd(&c[e.z >> 18], 1);
        atomicAdd(&c[e.w >> 18], 1);
        int j = q << 2;
        if (j + 3 < STAGECAP) {
            stage[j] = e.x; stage[j + 1] = e.y; stage[j + 2] = e.z; stage[j + 3] = e.w;
        }
    }
    for (int j = (vc << 2) + tid; j < cnt; j += 512) {
        uint e = eb[j];
        atomicAdd(&c[e >> 18], 1);
        if (j < STAGECAP) stage[j] = e;
    }
    __syncthreads();
    // scan 512 counters: 64 lanes x 8 each (wave 0)
    if (tid < 64) {
        int lo = tid * 8, s = 0;
#pragma unroll
        for (int k = 0; k < 8; ++k) s += c[lo + k];
        int v = s;
        for (int o = 1; o < 64; o <<= 1) {
            int u = __shfl_up(v, o, 64);
            if (tid >= o) v += u;
        }
        int excl = v - s;
#pragma unroll
        for (int k = 0; k < 8; ++k) { off[lo + k] = excl; excl += c[lo + k]; }
    }
    __syncthreads();
    // per-node metadata + degree binning
    for (int t = tid; t < BNODES; t += 512) {
        cur[t] = off[t];
        int node = (b << SH) + t;
        if (node < N) {
            rowptr[node] = cbase + off[t];
            float di = rsqrtf((float)c[t] + 1.0f);
            dinv[node] = di;
            float2 xv = ((const float2*)x)[node];
            p1[node] = make_float2(xv.x * di, xv.y * di);
        }
        if (t < nnodes) atomicAdd(&dbin[min(c[t], 63)], 1);
    }
    __syncthreads();
    // scan 64 degree bins (wave 0)
    if (tid < 64) {
        int orig = dbin[tid];
        int v = orig;
        for (int o = 1; o < 64; o <<= 1) {
            int u = __shfl_up(v, o, 64);
            if (tid >= o) v += u;
        }
        dcur[tid] = v - orig;
    }
    __syncthreads();
    // degree-sorted permutation (invalid tail slots -> sentinel >= N)
    for (int t = tid; t < BNODES; t += 512) {
        if (t < nnodes) {
            int r = atomicAdd(&dcur[min(c[t], 63)], 1);
            nodeperm[(b << SH) + r] = (b << SH) + t;
        } else {
            nodeperm[(b << SH) + t] = N;   // guard value
        }
    }
    __syncthreads();
    // placement pass: read from LDS stage (global fallback past STAGECAP)
    int lim = min(cnt, STAGECAP);
    for (int j = tid; j < lim; j += 512) {
        uint e = stage[j];
        int dl = e >> 18;
        int pos = atomicAdd(&cur[dl], 1);
        col[cbase + pos] = (int)(e & 0x3FFFF);
    }
    for (int j = STAGECAP + tid; j < cnt; j += 512) {
        uint e = eb[j];
        int dl = e >> 18;
        int pos = atomicAdd(&cur[dl], 1);
        col[cbase + pos] = (int)(e & 0x3FFFF);
    }
}

// ---- FUSED layer-1 gather + W1/ReLU/W2/pre-scale -> packed bf16 p2 rows ----
// Degree-sorted node order via nodeperm: waves carry equal-degree nodes.
__global__ void __launch_bounds__(256) k_gl12(
        const int* __restrict__ nodeperm,
        const int* __restrict__ rowptr, const int* __restrict__ col,
        const float2* __restrict__ p1, const float* __restrict__ dinv,
        const float* __restrict__ W1, const float* __restrict__ b1,
        const float* __restrict__ W2, uint* __restrict__ p2h, int N, int NTOT) {
    __shared__ float sW1[64], sb1[32], sW2[HID * HID];
    int tid = threadIdx.x;
    for (int t = tid; t < HID * HID; t += 256) sW2[t] = W2[t];
    if (tid < 64) sW1[tid] = W1[tid];
    if (tid < 32) sb1[tid] = b1[tid];
    __syncthreads();
    int idx = blockIdx.x * 16 + (tid >> 4);
    if (idx >= NTOT) return;
    int i = nodeperm[idx];
    if (i >= N) return;
    int sub = tid & 15;

    int beg = rowptr[i], end = rowptr[i + 1];
    float ax = 0, ay = 0, bx = 0, by = 0;
    int j = beg + sub;
    for (; j + 16 < end; j += 32) {
        int c0 = col[j], c1 = col[j + 16];
        float2 v0 = p1[c0], v1 = p1[c1];
        ax += v0.x; ay += v0.y;
        bx += v1.x; by += v1.y;
    }
    if (j < end) {
        float2 v = p1[col[j]];
        ax += v.x; ay += v.y;
    }
    float sx = ax + bx, sy = ay + by;
#pragma unroll
    for (int m = 1; m < 16; m <<= 1) {
        sx += __shfl_xor(sx, m, 16);
        sy += __shfl_xor(sy, m, 16);
    }

    float2 a = p1[i];
    float di = dinv[i];
    float g0 = di * (a.x + sx);
    float g1 = di * (a.y + sy);

    float h0 = fmaxf(g0 * sW1[2 * sub] + g1 * sW1[32 + 2 * sub] + sb1[2 * sub], 0.0f);
    float h1 = fmaxf(g0 * sW1[2 * sub + 1] + g1 * sW1[32 + 2 * sub + 1] + sb1[2 * sub + 1], 0.0f);

    float o0 = 0, o1 = 0;
    int fb = 2 * sub;
#pragma unroll
    for (int s = 0; s < 16; ++s) {
        float hk0 = __shfl(h0, s, 16);
        float hk1 = __shfl(h1, s, 16);
        const float* w0 = &sW2[(2 * s) * HID + fb];
        const float* w1 = &sW2[(2 * s + 1) * HID + fb];
        o0 += hk0 * w0[0]; o1 += hk0 * w0[1];
        o0 += hk1 * w1[0]; o1 += hk1 * w1[1];
    }

    p2h[(long)i * 16 + sub] = f2bf(di * o0) | (f2bf(di * o1) << 16);
}

// ---- layer-2 bf16 row gather: 16 lanes/node x 2 features, 8-way unrolled, degree-sorted ----
__global__ void k_gout(const int* __restrict__ nodeperm,
                       const int* __restrict__ rowptr, const int* __restrict__ col,
                       const uint* __restrict__ p2h, const float* __restrict__ b2,
                       const float* __restrict__ Wp, const float* __restrict__ bp,
                       const float* __restrict__ dinv, float* __restrict__ out,
                       int N, int NTOT) {
    int idx = blockIdx.x * 16 + (threadIdx.x >> 4);
    if (idx >= NTOT) return;
    int node = nodeperm[idx];
    if (node >= N) return;
    int hl = threadIdx.x & 15;   // owns features 2*hl, 2*hl+1
    int beg = rowptr[node], end = rowptr[node + 1];
    uint w = p2h[(long)node * 16 + hl];  // self term
    float sA0 = __uint_as_float(w << 16), sB0 = __uint_as_float(w & 0xffff0000u);
    float sA1 = 0, sB1 = 0, sA2 = 0, sB2 = 0, sA3 = 0, sB3 = 0;
    float sA4 = 0, sB4 = 0, sA5 = 0, sB5 = 0, sA6 = 0, sB6 = 0, sA7 = 0, sB7 = 0;
    int j = beg;
    for (; j + 8 <= end; j += 8) {
        int c0 = col[j],     c1 = col[j + 1], c2 = col[j + 2], c3 = col[j + 3];
        int c4 = col[j + 4], c5 = col[j + 5], c6 = col[j + 6], c7 = col[j + 7];
        uint w0 = p2h[(long)c0 * 16 + hl];
        uint w1 = p2h[(long)c1 * 16 + hl];
        uint w2 = p2h[(long)c2 * 16 + hl];
        uint w3 = p2h[(long)c3 * 16 + hl];
        uint w4 = p2h[(long)c4 * 16 + hl];
        uint w5 = p2h[(long)c5 * 16 + hl];
        uint w6 = p2h[(long)c6 * 16 + hl];
        uint w7 = p2h[(long)c7 * 16 + hl];
        sA0 += __uint_as_float(w0 << 16); sB0 += __uint_as_float(w0 & 0xffff0000u);
        sA1 += __uint_as_float(w1 << 16); sB1 += __uint_as_float(w1 & 0xffff0000u);
        sA2 += __uint_as_float(w2 << 16); sB2 += __uint_as_float(w2 & 0xffff0000u);
        sA3 += __uint_as_float(w3 << 16); sB3 += __uint_as_float(w3 & 0xffff0000u);
        sA4 += __uint_as_float(w4 << 16); sB4 += __uint_as_float(w4 & 0xffff0000u);
        sA5 += __uint_as_float(w5 << 16); sB5 += __uint_as_float(w5 & 0xffff0000u);
        sA6 += __uint_as_float(w6 << 16); sB6 += __uint_as_float(w6 & 0xffff0000u);
        sA7 += __uint_as_float(w7 << 16); sB7 += __uint_as_float(w7 & 0xffff0000u);
    }
    for (; j + 4 <= end; j += 4) {
        int c0 = col[j], c1 = col[j + 1], c2 = col[j + 2], c3 = col[j + 3];
        uint w0 = p2h[(long)c0 * 16 + hl];
        uint w1 = p2h[(long)c1 * 16 + hl];
        uint w2 = p2h[(long)c2 * 16 + hl];
        uint w3 = p2h[(long)c3 * 16 + hl];
        sA0 += __uint_as_float(w0 << 16); sB0 += __uint_as_float(w0 & 0xffff0000u);
        sA1 += __uint_as_float(w1 << 16); sB1 += __uint_as_float(w1 & 0xffff0000u);
        sA2 += __uint_as_float(w2 << 16); sB2 += __uint_as_float(w2 & 0xffff0000u);
        sA3 += __uint_as_float(w3 << 16); sB3 += __uint_as_float(w3 & 0xffff0000u);
    }
    for (; j < end; ++j) {
        uint wj = p2h[(long)col[j] * 16 + hl];
        sA0 += __uint_as_float(wj << 16); sB0 += __uint_as_float(wj & 0xffff0000u);
    }
    float sA = ((sA0 + sA1) + (sA2 + sA3)) + ((sA4 + sA5) + (sA6 + sA7));
    float sB = ((sB0 + sB1) + (sB2 + sB3)) + ((sB4 + sB5) + (sB6 + sB7));
    float di = dinv[node];
    float hvA = fmaxf(di * sA + b2[2 * hl], 0.0f);
    float hvB = fmaxf(di * sB + b2[2 * hl + 1], 0.0f);
    float v = hvA * Wp[2 * hl] + hvB * Wp[2 * hl + 1];
#pragma unroll
    for (int m = 8; m > 0; m >>= 1) v += __shfl_xor(v, m, 16);
    if (hl == 0) out[node] = 1.0f / (1.0f + expf(-(v + bp[0])));
}

extern "C" void kernel_launch(void* const* d_in, const int* in_sizes, int n_in,
                              void* d_out, int out_size, void* d_ws, size_t ws_size,
                              hipStream_t stream) {
    const float* x  = (const float*)d_in[0];
    const int*   ei = (const int*)d_in[1];
    const float* W1 = (const float*)d_in[2];
    const float* b1 = (const float*)d_in[3];
    const float* W2 = (const float*)d_in[4];
    const float* b2 = (const float*)d_in[5];
    const float* Wp = (const float*)d_in[6];
    const float* bp = (const float*)d_in[7];
    float* out = (float*)d_out;

    const int N = in_sizes[0] / 2;   // IN_DIM = 2
    const int E = in_sizes[1] / 2;   // edge_index is [2, E]
    const int* src = ei;
    const int* dst = ei + E;
    const int NB = (N + BNODES - 1) >> SH;   // 293
    const int NTOT = NB << SH;               // 150016

    char* ws = (char*)d_ws;
    size_t off = 0;
    auto alloc = [&](size_t bytes) {
        void* ptr = ws + off;
        off += (bytes + 255) & ~(size_t)255;
        return ptr;
    };
    int*    bcur     = (int*)alloc((size_t)NBMAX * 4);
    int*    bbase    = (int*)alloc((size_t)(NBMAX + 1) * 4);
    int*    rowptr   = (int*)alloc((size_t)(N + 1) * 4);
    float*  dinv     = (float*)alloc((size_t)N * 4);
    uint*   ebuf     = (uint*)alloc((size_t)NBMAX * CAP * 4);   // ~21 MB
    int*    col      = (int*)alloc((size_t)E * 4);
    float2* p1       = (float2*)alloc((size_t)N * 8);
    uint*   p2h      = (uint*)alloc((size_t)N * 16 * 4);
    int*    nodeperm = (int*)alloc((size_t)(NB << SH) * 4);

    const int nb_t = (E + TILE - 1) / TILE;
    const int nb_p = (NTOT + 15) / 16;   // 9376 blocks, 16 perm-slots each

    k_zero<<<(NBMAX + 255) / 256, 256, 0, stream>>>(bcur, NBMAX);
    k_bucketize<<<nb_t, 512, 0, stream>>>(src, dst, bcur, ebuf, E, NB);
    k_scanb<<<1, 256, 0, stream>>>(bcur, bbase, rowptr, N, NB);
    k_sortb<<<NB, 512, 0, stream>>>(ebuf, bcur, bbase, x, rowptr, dinv, p1, col, nodeperm, N);
    k_gl12<<<nb_p, 256, 0, stream>>>(nodeperm, rowptr, col, p1, dinv, W1, b1, W2, p2h, N, NTOT);
    k_gout<<<nb_p, 256, 0, stream>>>(nodeperm, rowptr, col, p2h, b2, Wp, bp, dinv, out, N, NTOT);
}

// Round 25
// 115.839 us; speedup vs baseline: 1.1181x; 1.1181x over previous
//
#include <hip/hip_runtime.h>

#define HID 32
#define SH 9                 // bucket covers 512 nodes
#define BNODES 512
#define NBMAX 320            // >= ceil(150000/512)=293
#define TILE 8192            // edges per bucketize block
#define CAP 16384            // fixed ebuf capacity per bucket (2x mean load)
#define STAGECAP 12288       // LDS edge staging in k_sortb (48 KB)

typedef unsigned int uint;

__device__ __forceinline__ uint f2bf(float v) {   // RNE f32 -> bf16 bits
    uint b = __float_as_uint(v);
    return (b + 0x7fffu + ((b >> 16) & 1u)) >> 16;
}

// ---- zero bcur ----
__global__ void k_zero(int* __restrict__ p, int n) {
    int i = blockIdx.x * 256 + threadIdx.x;
    if (i < n) p[i] = 0;
}

// ---- bucketize: int4 loads -> LDS counting sort by bucket -> bump-allocated chunk append ----
// ebuf layout: bucket b owns slots [b*CAP, b*CAP + bcur[b]). packed word: src | (dlow<<18)
__global__ void __launch_bounds__(512) k_bucketize(
        const int* __restrict__ src, const int* __restrict__ dst,
        int* __restrict__ bcur, uint* __restrict__ ebuf, int E, int NB) {
    __shared__ uint  ecache[TILE];
    __shared__ unsigned short bcache[TILE];
    __shared__ int cnt[NBMAX];
    __shared__ int loff[NBMAX + 1];
    __shared__ int gbase[NBMAX];
    int tid = threadIdx.x;
    int tbase = blockIdx.x * TILE;
    int tcount = min(E - tbase, TILE);
    int tc4 = tcount >> 2;
    const int4* dst4 = (const int4*)(dst + tbase);
    const int4* src4 = (const int4*)(src + tbase);

    for (int b = tid; b < NBMAX; b += 512) cnt[b] = 0;
    __syncthreads();
    // phase 1: count (vectorized)
#pragma unroll
    for (int k = 0; k < TILE / 4 / 512; ++k) {
        int q = k * 512 + tid;
        if (q < tc4) {
            int4 d = dst4[q];
            atomicAdd(&cnt[d.x >> SH], 1);
            atomicAdd(&cnt[d.y >> SH], 1);
            atomicAdd(&cnt[d.z >> SH], 1);
            atomicAdd(&cnt[d.w >> SH], 1);
        }
    }
    if (tid == 0)
        for (int t = tc4 << 2; t < tcount; ++t) atomicAdd(&cnt[dst[tbase + t] >> SH], 1);
    __syncthreads();
    // phase 2: scan (wave 0), 64 lanes x 5 buckets
    if (tid < 64) {
        int lo = tid * 5;
        int s = 0;
        for (int b = lo; b < lo + 5 && b < NB; ++b) s += cnt[b];
        int v = s;
        for (int off = 1; off < 64; off <<= 1) {
            int u = __shfl_up(v, off, 64);
            if (tid >= off) v += u;
        }
        int excl = v - s;
        for (int b = lo; b < lo + 5 && b < NB; ++b) { loff[b] = excl; excl += cnt[b]; }
        if (tid == 63) loff[NB] = excl;
    }
    __syncthreads();
    for (int b = tid; b < NB; b += 512) cnt[b] = loff[b];
    __syncthreads();
    // phase 3: place into LDS ordered by bucket (vectorized loads)
#pragma unroll
    for (int k = 0; k < TILE / 4 / 512; ++k) {
        int q = k * 512 + tid;
        if (q < tc4) {
            int4 d = dst4[q];
            int4 s = src4[q];
            int b0 = d.x >> SH, p0 = atomicAdd(&cnt[b0], 1);
            ecache[p0] = (uint)s.x | ((uint)(d.x & (BNODES - 1)) << 18); bcache[p0] = (unsigned short)b0;
            int b1 = d.y >> SH, p1_ = atomicAdd(&cnt[b1], 1);
            ecache[p1_] = (uint)s.y | ((uint)(d.y & (BNODES - 1)) << 18); bcache[p1_] = (unsigned short)b1;
            int b2 = d.z >> SH, p2_ = atomicAdd(&cnt[b2], 1);
            ecache[p2_] = (uint)s.z | ((uint)(d.z & (BNODES - 1)) << 18); bcache[p2_] = (unsigned short)b2;
            int b3 = d.w >> SH, p3_ = atomicAdd(&cnt[b3], 1);
            ecache[p3_] = (uint)s.w | ((uint)(d.w & (BNODES - 1)) << 18); bcache[p3_] = (unsigned short)b3;
        }
    }
    if (tid == 0)
        for (int t = tc4 << 2; t < tcount; ++t) {
            int d = dst[tbase + t];
            int b_ = d >> SH;
            int pos = atomicAdd(&cnt[b_], 1);
            ecache[pos] = (uint)src[tbase + t] | ((uint)(d & (BNODES - 1)) << 18);
            bcache[pos] = (unsigned short)b_;
        }
    __syncthreads();
    // phase 4: reserve chunk in fixed-stride bucket region (bump allocator)
    for (int b = tid; b < NB; b += 512) {
        int tc = loff[b + 1] - loff[b];
        if (tc > 0) gbase[b] = b * CAP + atomicAdd(&bcur[b], tc);
    }
    __syncthreads();
    // phase 5: contiguous write-out
    for (int j = tid; j < tcount; j += 512) {
        int b = bcache[j];
        ebuf[gbase[b] + (j - loff[b])] = ecache[j];
    }
}

// ---- per-bucket counting sort by node, LDS-staged; computes own CSR base (no scanb) ----
__global__ void __launch_bounds__(512) k_sortb(
        const uint* __restrict__ ebuf, const int* __restrict__ bcur,
        const float* __restrict__ x,
        int* __restrict__ rowptr, float* __restrict__ dinv,
        float2* __restrict__ p1, int* __restrict__ col, int N, int NB) {
    __shared__ int c[BNODES];
    __shared__ int off[BNODES];
    __shared__ int cur[BNODES];
    __shared__ int sh_cbase;
    __shared__ uint stage[STAGECAP];   // 48 KB edge staging
    int b = blockIdx.x, tid = threadIdx.x;
    int cnt = bcur[b];
    const uint* eb = ebuf + (long)b * CAP;   // 16B-aligned (CAP % 4 == 0)
    for (int t = tid; t < BNODES; t += 512) c[t] = 0;
    // CSR base = sum of bcur[0..b-1], wave 1 (lanes 64..127) computes while others zero
    if (tid >= 64 && tid < 128) {
        int lane = tid - 64;
        int s = 0;
        for (int q = lane; q < b; q += 64) s += bcur[q];
#pragma unroll
        for (int o = 1; o < 64; o <<= 1) s += __shfl_xor(s, o, 64);
        if (lane == 0) sh_cbase = s;
    }
    __syncthreads();
    int cbase = sh_cbase;
    // count pass: uint4 loads, stage into LDS
    int vc = cnt >> 2;
    const uint4* e4 = (const uint4*)eb;
    for (int q = tid; q < vc; q += 512) {
        uint4 e = e4[q];
        atomicAdd(&c[e.x >> 18], 1);
        atomicAdd(&c[e.y >> 18], 1);
        atomicAdd(&c[e.z >> 18], 1);
        atomicAdd(&c[e.w >> 18], 1);
        int j = q << 2;
        if (j + 3 < STAGECAP) {
            stage[j] = e.x; stage[j + 1] = e.y; stage[j + 2] = e.z; stage[j + 3] = e.w;
        }
    }
    for (int j = (vc << 2) + tid; j < cnt; j += 512) {
        uint e = eb[j];
        atomicAdd(&c[e >> 18], 1);
        if (j < STAGECAP) stage[j] = e;
    }
    __syncthreads();
    // scan 512 counters: 64 lanes x 8 each (wave 0)
    if (tid < 64) {
        int lo = tid * 8, s = 0;
#pragma unroll
        for (int k = 0; k < 8; ++k) s += c[lo + k];
        int v = s;
        for (int o = 1; o < 64; o <<= 1) {
            int u = __shfl_up(v, o, 64);
            if (tid >= o) v += u;
        }
        int excl = v - s;
#pragma unroll
        for (int k = 0; k < 8; ++k) { off[lo + k] = excl; excl += c[lo + k]; }
    }
    __syncthreads();
    for (int t = tid; t < BNODES; t += 512) {
        cur[t] = off[t];
        int node = (b << SH) + t;
        if (node < N) {
            rowptr[node] = cbase + off[t];
            float di = rsqrtf((float)c[t] + 1.0f);
            dinv[node] = di;
            float2 xv = ((const float2*)x)[node];
            p1[node] = make_float2(xv.x * di, xv.y * di);
        }
    }
    if (b == NB - 1 && tid == 0) rowptr[N] = cbase + cnt;   // CSR terminator
    __syncthreads();
    // placement pass: read from LDS stage (global fallback past STAGECAP)
    int lim = min(cnt, STAGECAP);
    for (int j = tid; j < lim; j += 512) {
        uint e = stage[j];
        int dl = e >> 18;
        int pos = atomicAdd(&cur[dl], 1);
        col[cbase + pos] = (int)(e & 0x3FFFF);
    }
    for (int j = STAGECAP + tid; j < cnt; j += 512) {
        uint e = eb[j];
        int dl = e >> 18;
        int pos = atomicAdd(&cur[dl], 1);
        col[cbase + pos] = (int)(e & 0x3FFFF);
    }
}

// ---- FUSED layer-1 gather + W1/ReLU/W2/pre-scale -> packed bf16 p2 rows ----
__global__ void __launch_bounds__(256) k_gl12(
        const int* __restrict__ rowptr, const int* __restrict__ col,
        const float2* __restrict__ p1, const float* __restrict__ dinv,
        const float* __restrict__ W1, const float* __restrict__ b1,
        const float* __restrict__ W2, uint* __restrict__ p2h, int N) {
    __shared__ float sW1[64], sb1[32], sW2[HID * HID];
    int tid = threadIdx.x;
    for (int t = tid; t < HID * HID; t += 256) sW2[t] = W2[t];
    if (tid < 64) sW1[tid] = W1[tid];
    if (tid < 32) sb1[tid] = b1[tid];
    __syncthreads();
    int i = blockIdx.x * 16 + (tid >> 4);
    if (i >= N) return;
    int sub = tid & 15;

    int beg = rowptr[i], end = rowptr[i + 1];
    float ax = 0, ay = 0, bx = 0, by = 0;
    int j = beg + sub;
    for (; j + 16 < end; j += 32) {
        int c0 = col[j], c1 = col[j + 16];
        float2 v0 = p1[c0], v1 = p1[c1];
        ax += v0.x; ay += v0.y;
        bx += v1.x; by += v1.y;
    }
    if (j < end) {
        float2 v = p1[col[j]];
        ax += v.x; ay += v.y;
    }
    float sx = ax + bx, sy = ay + by;
#pragma unroll
    for (int m = 1; m < 16; m <<= 1) {
        sx += __shfl_xor(sx, m, 16);
        sy += __shfl_xor(sy, m, 16);
    }

    float2 a = p1[i];
    float di = dinv[i];
    float g0 = di * (a.x + sx);
    float g1 = di * (a.y + sy);

    float h0 = fmaxf(g0 * sW1[2 * sub] + g1 * sW1[32 + 2 * sub] + sb1[2 * sub], 0.0f);
    float h1 = fmaxf(g0 * sW1[2 * sub + 1] + g1 * sW1[32 + 2 * sub + 1] + sb1[2 * sub + 1], 0.0f);

    float o0 = 0, o1 = 0;
    int fb = 2 * sub;
#pragma unroll
    for (int s = 0; s < 16; ++s) {
        float hk0 = __shfl(h0, s, 16);
        float hk1 = __shfl(h1, s, 16);
        const float* w0 = &sW2[(2 * s) * HID + fb];
        const float* w1 = &sW2[(2 * s + 1) * HID + fb];
        o0 += hk0 * w0[0]; o1 += hk0 * w0[1];
        o0 += hk1 * w1[0]; o1 += hk1 * w1[1];
    }

    p2h[(long)i * 16 + sub] = f2bf(di * o0) | (f2bf(di * o1) << 16);
}

// ---- layer-2 bf16 row gather: 16 lanes/node x 2 features, 8-way unrolled ----
__global__ void k_gout(const int* __restrict__ rowptr, const int* __restrict__ col,
                       const uint* __restrict__ p2h, const float* __restrict__ b2,
                       const float* __restrict__ Wp, const float* __restrict__ bp,
                       const float* __restrict__ dinv, float* __restrict__ out, int N) {
    int node = blockIdx.x * 16 + (threadIdx.x >> 4);
    if (node >= N) return;
    int hl = threadIdx.x & 15;   // owns features 2*hl, 2*hl+1
    int beg = rowptr[node], end = rowptr[node + 1];
    uint w = p2h[(long)node * 16 + hl];  // self term
    float sA0 = __uint_as_float(w << 16), sB0 = __uint_as_float(w & 0xffff0000u);
    float sA1 = 0, sB1 = 0, sA2 = 0, sB2 = 0, sA3 = 0, sB3 = 0;
    float sA4 = 0, sB4 = 0, sA5 = 0, sB5 = 0, sA6 = 0, sB6 = 0, sA7 = 0, sB7 = 0;
    int j = beg;
    for (; j + 8 <= end; j += 8) {
        int c0 = col[j],     c1 = col[j + 1], c2 = col[j + 2], c3 = col[j + 3];
        int c4 = col[j + 4], c5 = col[j + 5], c6 = col[j + 6], c7 = col[j + 7];
        uint w0 = p2h[(long)c0 * 16 + hl];
        uint w1 = p2h[(long)c1 * 16 + hl];
        uint w2 = p2h[(long)c2 * 16 + hl];
        uint w3 = p2h[(long)c3 * 16 + hl];
        uint w4 = p2h[(long)c4 * 16 + hl];
        uint w5 = p2h[(long)c5 * 16 + hl];
        uint w6 = p2h[(long)c6 * 16 + hl];
        uint w7 = p2h[(long)c7 * 16 + hl];
        sA0 += __uint_as_float(w0 << 16); sB0 += __uint_as_float(w0 & 0xffff0000u);
        sA1 += __uint_as_float(w1 << 16); sB1 += __uint_as_float(w1 & 0xffff0000u);
        sA2 += __uint_as_float(w2 << 16); sB2 += __uint_as_float(w2 & 0xffff0000u);
        sA3 += __uint_as_float(w3 << 16); sB3 += __uint_as_float(w3 & 0xffff0000u);
        sA4 += __uint_as_float(w4 << 16); sB4 += __uint_as_float(w4 & 0xffff0000u);
        sA5 += __uint_as_float(w5 << 16); sB5 += __uint_as_float(w5 & 0xffff0000u);
        sA6 += __uint_as_float(w6 << 16); sB6 += __uint_as_float(w6 & 0xffff0000u);
        sA7 += __uint_as_float(w7 << 16); sB7 += __uint_as_float(w7 & 0xffff0000u);
    }
    for (; j + 4 <= end; j += 4) {
        int c0 = col[j], c1 = col[j + 1], c2 = col[j + 2], c3 = col[j + 3];
        uint w0 = p2h[(long)c0 * 16 + hl];
        uint w1 = p2h[(long)c1 * 16 + hl];
        uint w2 = p2h[(long)c2 * 16 + hl];
        uint w3 = p2h[(long)c3 * 16 + hl];
        sA0 += __uint_as_float(w0 << 16); sB0 += __uint_as_float(w0 & 0xffff0000u);
        sA1 += __uint_as_float(w1 << 16); sB1 += __uint_as_float(w1 & 0xffff0000u);
        sA2 += __uint_as_float(w2 << 16); sB2 += __uint_as_float(w2 & 0xffff0000u);
        sA3 += __uint_as_float(w3 << 16); sB3 += __uint_as_float(w3 & 0xffff0000u);
    }
    for (; j < end; ++j) {
        uint wj = p2h[(long)col[j] * 16 + hl];
        sA0 += __uint_as_float(wj << 16); sB0 += __uint_as_float(wj & 0xffff0000u);
    }
    float sA = ((sA0 + sA1) + (sA2 + sA3)) + ((sA4 + sA5) + (sA6 + sA7));
    float sB = ((sB0 + sB1) + (sB2 + sB3)) + ((sB4 + sB5) + (sB6 + sB7));
    float di = dinv[node];
    float hvA = fmaxf(di * sA + b2[2 * hl], 0.0f);
    float hvB = fmaxf(di * sB + b2[2 * hl + 1], 0.0f);
    float v = hvA * Wp[2 * hl] + hvB * Wp[2 * hl + 1];
#pragma unroll
    for (int m = 8; m > 0; m >>= 1) v += __shfl_xor(v, m, 16);
    if (hl == 0) out[node] = 1.0f / (1.0f + expf(-(v + bp[0])));
}

extern "C" void kernel_launch(void* const* d_in, const int* in_sizes, int n_in,
                              void* d_out, int out_size, void* d_ws, size_t ws_size,
                              hipStream_t stream) {
    const float* x  = (const float*)d_in[0];
    const int*   ei = (const int*)d_in[1];
    const float* W1 = (const float*)d_in[2];
    const float* b1 = (const float*)d_in[3];
    const float* W2 = (const float*)d_in[4];
    const float* b2 = (const float*)d_in[5];
    const float* Wp = (const float*)d_in[6];
    const float* bp = (const float*)d_in[7];
    float* out = (float*)d_out;

    const int N = in_sizes[0] / 2;   // IN_DIM = 2
    const int E = in_sizes[1] / 2;   // edge_index is [2, E]
    const int* src = ei;
    const int* dst = ei + E;
    const int NB = (N + BNODES - 1) >> SH;   // 293

    char* ws = (char*)d_ws;
    size_t off = 0;
    auto alloc = [&](size_t bytes) {
        void* ptr = ws + off;
        off += (bytes + 255) & ~(size_t)255;
        return ptr;
    };
    int*    bcur   = (int*)alloc((size_t)NBMAX * 4);
    int*    rowptr = (int*)alloc((size_t)(N + 1) * 4);
    float*  dinv   = (float*)alloc((size_t)N * 4);
    uint*   ebuf   = (uint*)alloc((size_t)NBMAX * CAP * 4);   // fixed-stride buckets, ~21 MB
    int*    col    = (int*)alloc((size_t)E * 4);
    float2* p1     = (float2*)alloc((size_t)N * 8);
    uint*   p2h    = (uint*)alloc((size_t)N * 16 * 4);

    const int nb_t = (E + TILE - 1) / TILE;
    const int nb_g = (N + 15) / 16;

    k_zero<<<(NBMAX + 255) / 256, 256, 0, stream>>>(bcur, NBMAX);
    k_bucketize<<<nb_t, 512, 0, stream>>>(src, dst, bcur, ebuf, E, NB);
    k_sortb<<<NB, 512, 0, stream>>>(ebuf, bcur, x, rowptr, dinv, p1, col, N, NB);
    k_gl12<<<nb_g, 256, 0, stream>>>(rowptr, col, p1, dinv, W1, b1, W2, p2h, N);
    k_gout<<<nb_g, 256, 0, stream>>>(rowptr, col, p2h, b2, Wp, bp, dinv, out, N);
}